// Round 2
// baseline (612.384 us; speedup 1.0000x reference)
//
#include <hip/hip_runtime.h>

// Fused MS-SSIM + L1, single pass over X,Y. B=128, H=W=384 fp32.
// Levels K=1,2,4,7, box conv, zero pad p=K/2. Even K -> output 385x385.
// Per wave: 64 lanes = 64 horizontal window-start columns (stride 56, 8 halo),
// rows iterated sequentially. Horizontal sums via ds_bpermute hierarchy,
// vertical sums via per-lane register history. Level 1 closed form.

#define W 384
#define H 384
#define NB 128
#define BAND 49
#define NBANDS 8
#define NTILES 7

__global__ void zero_acc_kernel(double* acc) {
    if (threadIdx.x < 5) acc[threadIdx.x] = 0.0;
}

__device__ __forceinline__ float shdn(int addr, float v) {
    return __int_as_float(__builtin_amdgcn_ds_bpermute(addr, __float_as_int(v)));
}

__device__ __forceinline__ float ssim_term(const float V[5], float inv, float C1, float C2) {
    const float ux = V[0] * inv, uy = V[1] * inv;
    const float uxx = V[2] * inv, uyy = V[3] * inv, uxy = V[4] * inv;
    const float vx = uxx - ux * ux;
    const float vy = uyy - uy * uy;
    const float vxy = uxy - ux * uy;
    const float A = (2.f * ux * uy + C1) * (2.f * vxy + C2);
    const float B = (ux * ux + uy * uy + C1) * (vx + vy + C2);
    return A * __builtin_amdgcn_rcpf(B);
}

__global__ __launch_bounds__(64) void msssim_fused_kernel(
    const float* __restrict__ X, const float* __restrict__ Y,
    const float* __restrict__ dr, double* __restrict__ acc)
{
    const int lane = threadIdx.x;
    const int tile = blockIdx.x;   // 0..6, column strips (stride 56)
    const int band = blockIdx.y;   // 0..7, row bands of 49 output rows
    const int b    = blockIdx.z;   // batch

    const int cbase = -3 + 56 * tile;   // window-start col of lane 0
    const int c     = cbase + lane;     // this lane's window-start col
    const int R0    = BAND * band;
    const int R1    = R0 + BAND;

    const float drb = dr[b];
    const float C1  = (0.01f * drb) * (0.01f * drb);
    const float C2  = (0.03f * drb) * (0.03f * drb);

    const bool cval = (c >= 0) && (c < W);
    // ownership: lane owns output col j=c+P iff 3-P <= lane <= 58-P and j < Wo
    const bool m1 = (lane >= 3) && (lane <= 58) && (c     < 384);
    const bool m2 = (lane >= 2) && (lane <= 57) && (c + 1 < 385);
    const bool m4 = (lane >= 1) && (lane <= 56) && (c + 2 < 385);
    const bool m7 =                (lane <= 55) && (c + 3 < 384);

    // precomputed bpermute byte addresses (lane+d)
    const int a1 = ((lane + 1) & 63) << 2;
    const int a2 = ((lane + 2) & 63) << 2;
    const int a4 = ((lane + 4) & 63) << 2;
    const int a6 = ((lane + 6) & 63) << 2;

    const float* __restrict__ Xp = X + (size_t)b * (H * W);
    const float* __restrict__ Yp = Y + (size_t)b * (H * W);

    // vertical histories (horizontal window sums of previous rows)
    float h2p[5];
    float h4p[3][5];
    float h7p[6][5];
#pragma unroll
    for (int q = 0; q < 5; ++q) {
        h2p[q] = 0.f;
        h4p[0][q] = h4p[1][q] = h4p[2][q] = 0.f;
#pragma unroll
        for (int a = 0; a < 6; ++a) h7p[a][q] = 0.f;
    }

    float ss1 = 0.f, ss2 = 0.f, ss4 = 0.f, ss7 = 0.f, l1 = 0.f;

    const int u0    = R0 - 3;
    const int u_end = (R1 + 2 < 386) ? (R1 + 2) : 386;

    // load first row (double-buffered)
    float xc = 0.f, yc = 0.f;
    if (cval && u0 >= 0 && u0 < H) {
        xc = Xp[(size_t)u0 * W + c];
        yc = Yp[(size_t)u0 * W + c];
    }

    for (int u = u0; u <= u_end; ++u) {
        // prefetch next row while computing current
        float xn = 0.f, yn = 0.f;
        const int un = u + 1;
        if (cval && un >= 0 && un < H) {
            xn = Xp[(size_t)un * W + c];
            yn = Yp[(size_t)un * W + c];
        }

        float r[5];
        r[0] = xc; r[1] = yc; r[2] = xc * xc; r[3] = yc * yc; r[4] = xc * yc;

        float V2[5], V4[5], V7[5];
#pragma unroll
        for (int q = 0; q < 5; ++q) {
            const float v  = r[q];
            const float w2 = v + shdn(a1, v);
            const float w4 = w2 + shdn(a2, w2);
            const float w7 = w4 + shdn(a4, w2) + shdn(a6, v);
            V2[q] = w2 + h2p[q];
            V4[q] = w4 + h4p[0][q] + h4p[1][q] + h4p[2][q];
            V7[q] = w7 + h7p[0][q] + h7p[1][q] + h7p[2][q]
                       + h7p[3][q] + h7p[4][q] + h7p[5][q];
            h2p[q] = w2;
            h4p[2][q] = h4p[1][q]; h4p[1][q] = h4p[0][q]; h4p[0][q] = w4;
            h7p[5][q] = h7p[4][q]; h7p[4][q] = h7p[3][q]; h7p[3][q] = h7p[2][q];
            h7p[2][q] = h7p[1][q]; h7p[1][q] = h7p[0][q]; h7p[0][q] = w7;
        }

        // level 1 (K=1): vx=vy=vxy=0 -> S = (2xy+C1)/(x^2+y^2+C1), row i=u
        if ((u >= R0) && (u < R1) && (u < 384)) {
            const float s = (2.f * r[4] + C1) * __builtin_amdgcn_rcpf(r[2] + r[3] + C1);
            if (m1) ss1 += s;
        }
        // level 2: row i=u (rows u-1..u)
        if ((u >= R0) && (u < R1) && (u < 385)) {
            const float s = ssim_term(V2, 0.25f, C1, C2);
            if (m2) ss2 += s;
        }
        // level 4: row i=u-1 (rows u-3..u)
        {
            const int i = u - 1;
            if ((i >= R0) && (i < R1) && (i < 385)) {
                const float s = ssim_term(V4, 0.0625f, C1, C2);
                if (m4) ss4 += s;
            }
        }
        // level 7: row i=u-3 (rows u-6..u) + L1 term
        {
            const int i = u - 3;
            if ((i >= R0) && (i < R1) && (i < 384)) {
                const float inv7 = 1.f / 49.f;
                const float ux = V7[0] * inv7, uy = V7[1] * inv7;
                const float uxx = V7[2] * inv7, uyy = V7[3] * inv7, uxy = V7[4] * inv7;
                const float vx = uxx - ux * ux;
                const float vy = uyy - uy * uy;
                const float vxy = uxy - ux * uy;
                const float A = (2.f * ux * uy + C1) * (2.f * vxy + C2);
                const float B = (ux * ux + uy * uy + C1) * (vx + vy + C2);
                const float s = A * __builtin_amdgcn_rcpf(B);
                if (m7) {
                    ss7 += s;
                    l1  += fabsf(ux - uy);
                }
            }
        }

        xc = xn; yc = yn;
    }

    // wave reduction
#pragma unroll
    for (int d = 32; d > 0; d >>= 1) {
        ss1 += __shfl_down(ss1, d, 64);
        ss2 += __shfl_down(ss2, d, 64);
        ss4 += __shfl_down(ss4, d, 64);
        ss7 += __shfl_down(ss7, d, 64);
        l1  += __shfl_down(l1,  d, 64);
    }
    if (lane == 0) {
        atomicAdd(&acc[0], (double)ss1);
        atomicAdd(&acc[1], (double)ss2);
        atomicAdd(&acc[2], (double)ss4);
        atomicAdd(&acc[3], (double)ss7);
        atomicAdd(&acc[4], (double)l1);
    }
}

__global__ void finalize_kernel(const double* __restrict__ acc, float* __restrict__ out) {
    const double n384 = (double)NB * 384.0 * 384.0;
    const double n385 = (double)NB * 385.0 * 385.0;
    const double m  = (acc[0] / n384) * (acc[1] / n385) * (acc[2] / n385) * (acc[3] / n384);
    const double l1 = acc[4] / n384;
    out[0] = (float)(0.84 * (1.0 - m) + 0.16 * l1);
}

extern "C" void kernel_launch(void* const* d_in, const int* in_sizes, int n_in,
                              void* d_out, int out_size, void* d_ws, size_t ws_size,
                              hipStream_t stream) {
    const float* X  = (const float*)d_in[0];
    const float* Y  = (const float*)d_in[1];
    const float* dr = (const float*)d_in[2];
    float* out  = (float*)d_out;
    double* acc = (double*)d_ws;

    zero_acc_kernel<<<1, 64, 0, stream>>>(acc);

    dim3 grid(NTILES, NBANDS, NB);
    msssim_fused_kernel<<<grid, 64, 0, stream>>>(X, Y, dr, acc);

    finalize_kernel<<<1, 1, 0, stream>>>(acc, out);
}